// Round 1
// baseline (9947.627 us; speedup 1.0000x reference)
//
#include <hip/hip_runtime.h>
#include <hip/hip_bf16.h>

// Problem constants
#define B_   4
#define T_   2048
#define E_   1024
#define NH_  16
#define HS_  64
#define F_   (3 * E_)   // 3072
#define M_   (B_ * T_)  // 8192

// ---------------- QKV projection GEMM: Y[M,F] = X[M,E] @ W[F,E]^T + b ----------------
#define BM 64
#define BN 64
#define BK 32

__global__ __launch_bounds__(256) void qkv_gemm(const float* __restrict__ X,
                                                const float* __restrict__ W,
                                                const float* __restrict__ bias,
                                                float* __restrict__ Y) {
    __shared__ float As[BM][BK + 1];
    __shared__ float Bs[BN][BK + 1];

    const int bn = blockIdx.x;   // F_/BN = 48
    const int bm = blockIdx.y;   // M_/BM = 128
    const int tid = threadIdx.x;
    const int tx = tid & 15;     // 0..15 -> N
    const int ty = tid >> 4;     // 0..15 -> M

    const int row0 = bm * BM;
    const int col0 = bn * BN;

    // loader mapping: each thread loads 8 consecutive floats (two float4) per tile
    const int lr = tid >> 2;          // 0..63
    const int lc = (tid & 3) * 8;     // 0,8,16,24

    float acc[4][4] = {};

    for (int k0 = 0; k0 < E_; k0 += BK) {
        const float4* xs = reinterpret_cast<const float4*>(&X[(long)(row0 + lr) * E_ + k0 + lc]);
        float4 a0 = xs[0], a1 = xs[1];
        const float4* ws = reinterpret_cast<const float4*>(&W[(long)(col0 + lr) * E_ + k0 + lc]);
        float4 b0 = ws[0], b1 = ws[1];

        __syncthreads();
        As[lr][lc + 0] = a0.x; As[lr][lc + 1] = a0.y; As[lr][lc + 2] = a0.z; As[lr][lc + 3] = a0.w;
        As[lr][lc + 4] = a1.x; As[lr][lc + 5] = a1.y; As[lr][lc + 6] = a1.z; As[lr][lc + 7] = a1.w;
        Bs[lr][lc + 0] = b0.x; Bs[lr][lc + 1] = b0.y; Bs[lr][lc + 2] = b0.z; Bs[lr][lc + 3] = b0.w;
        Bs[lr][lc + 4] = b1.x; Bs[lr][lc + 5] = b1.y; Bs[lr][lc + 6] = b1.z; Bs[lr][lc + 7] = b1.w;
        __syncthreads();

#pragma unroll
        for (int kk = 0; kk < BK; ++kk) {
            float a[4], b[4];
#pragma unroll
            for (int i = 0; i < 4; ++i) a[i] = As[ty * 4 + i][kk];
#pragma unroll
            for (int j = 0; j < 4; ++j) b[j] = Bs[tx * 4 + j][kk];
#pragma unroll
            for (int i = 0; i < 4; ++i)
#pragma unroll
                for (int j = 0; j < 4; ++j)
                    acc[i][j] += a[i] * b[j];
        }
    }

#pragma unroll
    for (int i = 0; i < 4; ++i) {
        const int r = row0 + ty * 4 + i;
#pragma unroll
        for (int j = 0; j < 4; ++j) {
            const int c = col0 + tx * 4 + j;
            Y[(long)r * F_ + c] = acc[i][j] + bias[c];
        }
    }
}

// ---------------- Attention: one wave per query row, online softmax ----------------
// qkv layout: [B, T, 3E]; q at f = h*64+d, k at E + h*64+d, v at 2E + h*64+d.
__global__ __launch_bounds__(256) void attn_rows(const float* __restrict__ qkv,
                                                 float* __restrict__ out) {
    const int wave = threadIdx.x >> 6;  // 0..3
    const int lane = threadIdx.x & 63;
    const long gr = (long)blockIdx.x * 4 + wave;  // 0 .. B*NH*T-1
    const int b = (int)(gr >> 15);                 // / (NH_*T_) = 32768
    const int rem = (int)(gr & 32767);
    const int h = rem >> 11;                       // / T_
    const int t = rem & (T_ - 1);

    const float* base = qkv + (long)b * T_ * F_;
    const float q = base[(long)t * F_ + h * HS_ + lane] * 0.125f;  // 1/sqrt(64)
    const float* kbase = base + E_ + h * HS_ + lane;
    const float* vbase = base + 2 * E_ + h * HS_ + lane;

    float m = -1e30f, l = 0.f, o = 0.f;

    for (int kk = 0; kk <= t; ++kk) {
        float kv = kbase[(long)kk * F_];
        float vv = vbase[(long)kk * F_];
        float prod = q * kv;
#pragma unroll
        for (int off = 32; off > 0; off >>= 1)
            prod += __shfl_xor(prod, off, 64);
        const float s = prod;
        const float mn = fmaxf(m, s);
        const float p = __expf(s - mn);
        const float scale = __expf(m - mn);
        l = l * scale + p;
        o = o * scale + p * vv;
        m = mn;
    }

    out[((long)b * T_ + t) * E_ + h * HS_ + lane] = o / l;
}

extern "C" void kernel_launch(void* const* d_in, const int* in_sizes, int n_in,
                              void* d_out, int out_size, void* d_ws, size_t ws_size,
                              hipStream_t stream) {
    const float* x     = (const float*)d_in[0];   // [4,2048,1024]
    const float* W_qkv = (const float*)d_in[1];   // [3072,1024]
    const float* b_qkv = (const float*)d_in[2];   // [3072]
    float* out = (float*)d_out;                   // [4,2048,1024]
    float* qkv = (float*)d_ws;                    // [8192,3072] = 96 MB

    dim3 ggrid(F_ / BN, M_ / BM);  // (48, 128)
    qkv_gemm<<<ggrid, 256, 0, stream>>>(x, W_qkv, b_qkv, qkv);

    const int total_rows = B_ * NH_ * T_;  // 131072
    attn_rows<<<total_rows / 4, 256, 0, stream>>>(qkv, out);
}

// Round 2
// 467.089 us; speedup vs baseline: 21.2971x; 21.2971x over previous
//
#include <hip/hip_runtime.h>
#include <hip/hip_bf16.h>

#define B_   4
#define T_   2048
#define E_   1024
#define NH_  16
#define HS_  64
#define F_   (3 * E_)   // 3072
#define M_   (B_ * T_)  // 8192

#define QBLK  128
#define KVBLK 64

typedef short bf16x8 __attribute__((ext_vector_type(8)));
typedef float f32x4 __attribute__((ext_vector_type(4)));

__device__ __forceinline__ short f2bf(float f) {
    __hip_bfloat16 h = __float2bfloat16(f);
    return *reinterpret_cast<short*>(&h);
}

__device__ __forceinline__ bf16x8 pack2(float4 a, float4 b) {
    bf16x8 r;
    r[0] = f2bf(a.x); r[1] = f2bf(a.y); r[2] = f2bf(a.z); r[3] = f2bf(a.w);
    r[4] = f2bf(b.x); r[5] = f2bf(b.y); r[6] = f2bf(b.z); r[7] = f2bf(b.w);
    return r;
}

// ---------------- QKV GEMM: Y[M,F] = X[M,E] @ W[F,E]^T + b, bf16 MFMA ----------------
__global__ __launch_bounds__(256) void qkv_gemm_mfma(const float* __restrict__ X,
                                                     const float* __restrict__ Wq,
                                                     const float* __restrict__ bias,
                                                     float* __restrict__ Y) {
    __shared__ __align__(16) short A_lds[128 * 64];
    __shared__ __align__(16) short B_lds[128 * 64];
    const int tid = threadIdx.x;
    const int w = tid >> 6, l = tid & 63, lg = l >> 4, lr = l & 15;
    const int wm = w >> 1, wn = w & 1;
    const int bm = blockIdx.y, bn = blockIdx.x;

    const f32x4 zero = {0.f, 0.f, 0.f, 0.f};
    f32x4 acc[4][4];
#pragma unroll
    for (int i = 0; i < 4; ++i)
#pragma unroll
        for (int j = 0; j < 4; ++j) acc[i][j] = zero;

    const int srow = tid >> 1, sd0 = (tid & 1) * 32;
    const float* xp = X + (long)(bm * 128 + srow) * E_ + sd0;
    const float* wp = Wq + (long)(bn * 128 + srow) * E_ + sd0;

    for (int k0 = 0; k0 < E_; k0 += 64) {
        __syncthreads();
#pragma unroll
        for (int c = 0; c < 4; ++c) {
            float4 u0 = *(const float4*)(xp + k0 + c * 8);
            float4 u1 = *(const float4*)(xp + k0 + c * 8 + 4);
            int ch = ((sd0 >> 3) + c) ^ (srow & 7);
            *(bf16x8*)&A_lds[srow * 64 + ch * 8] = pack2(u0, u1);
        }
#pragma unroll
        for (int c = 0; c < 4; ++c) {
            float4 u0 = *(const float4*)(wp + k0 + c * 8);
            float4 u1 = *(const float4*)(wp + k0 + c * 8 + 4);
            int ch = ((sd0 >> 3) + c) ^ (srow & 7);
            *(bf16x8*)&B_lds[srow * 64 + ch * 8] = pack2(u0, u1);
        }
        __syncthreads();

        bf16x8 af[4][2], bfr[4][2];
#pragma unroll
        for (int mg = 0; mg < 4; ++mg)
#pragma unroll
            for (int kk = 0; kk < 2; ++kk)
                af[mg][kk] = *(const bf16x8*)&A_lds[(wm * 64 + mg * 16 + lr) * 64 + ((kk * 4 + lg) ^ (lr & 7)) * 8];
#pragma unroll
        for (int ng = 0; ng < 4; ++ng)
#pragma unroll
            for (int kk = 0; kk < 2; ++kk)
                bfr[ng][kk] = *(const bf16x8*)&B_lds[(wn * 64 + ng * 16 + lr) * 64 + ((kk * 4 + lg) ^ (lr & 7)) * 8];

#pragma unroll
        for (int mg = 0; mg < 4; ++mg)
#pragma unroll
            for (int ng = 0; ng < 4; ++ng) {
                acc[mg][ng] = __builtin_amdgcn_mfma_f32_16x16x32_bf16(af[mg][0], bfr[ng][0], acc[mg][ng], 0, 0, 0);
                acc[mg][ng] = __builtin_amdgcn_mfma_f32_16x16x32_bf16(af[mg][1], bfr[ng][1], acc[mg][ng], 0, 0, 0);
            }
    }

#pragma unroll
    for (int mg = 0; mg < 4; ++mg)
#pragma unroll
        for (int ng = 0; ng < 4; ++ng)
#pragma unroll
            for (int r = 0; r < 4; ++r) {
                int row = bm * 128 + wm * 64 + mg * 16 + 4 * lg + r;
                int col = bn * 128 + wn * 64 + ng * 16 + lr;
                Y[(long)row * F_ + col] = acc[mg][ng][r] + bias[col];
            }
}

// ---------------- Flash attention, bf16 MFMA ----------------
// Block: one (b,h), 128 q-rows, 4 waves x 32 rows. KV tiles of 64 in LDS.
__global__ __launch_bounds__(256) void attn_mfma(const float* __restrict__ qkv,
                                                 float* __restrict__ out) {
    const int qt = blockIdx.x;      // 0..15
    const int bh = blockIdx.y;      // 0..63
    const int b = bh >> 4, h = bh & 15;
    const int tid = threadIdx.x;
    const int w = tid >> 6, l = tid & 63, lg = l >> 4, lr = l & 15;

    __shared__ __align__(16) short K_lds[KVBLK * 64];   // [key][dim] swizzled
    __shared__ __align__(16) short Vt_lds[64 * KVBLK];  // [dim][key] swizzled
    __shared__ __align__(16) short P_lds[4][32 * 64];   // per-wave [row][key] swizzled

    const float* base = qkv + (long)b * T_ * F_ + h * HS_;

    // Q fragments (pre-scaled by 1/sqrt(64))
    bf16x8 qf[2][2];
#pragma unroll
    for (int mg = 0; mg < 2; ++mg) {
        int qrow = qt * QBLK + w * 32 + mg * 16 + lr;
        const float* qp = base + (long)qrow * F_ + lg * 8;
#pragma unroll
        for (int kk = 0; kk < 2; ++kk) {
            float4 x0 = *(const float4*)(qp + kk * 32);
            float4 x1 = *(const float4*)(qp + kk * 32 + 4);
            bf16x8 f;
            f[0] = f2bf(x0.x * 0.125f); f[1] = f2bf(x0.y * 0.125f);
            f[2] = f2bf(x0.z * 0.125f); f[3] = f2bf(x0.w * 0.125f);
            f[4] = f2bf(x1.x * 0.125f); f[5] = f2bf(x1.y * 0.125f);
            f[6] = f2bf(x1.z * 0.125f); f[7] = f2bf(x1.w * 0.125f);
            qf[mg][kk] = f;
        }
    }

    const f32x4 zero = {0.f, 0.f, 0.f, 0.f};
    f32x4 o[2][4];
    float mrow[2][4], lrow[2][4];
#pragma unroll
    for (int mg = 0; mg < 2; ++mg)
#pragma unroll
        for (int r = 0; r < 4; ++r) { mrow[mg][r] = -1e30f; lrow[mg][r] = 0.f; }
#pragma unroll
    for (int mg = 0; mg < 2; ++mg)
#pragma unroll
        for (int n = 0; n < 4; ++n) o[mg][n] = zero;

    const int nkt = 2 * qt + 2;
    for (int kt = 0; kt < nkt; ++kt) {
        __syncthreads();
        // ---- stage K tile: thread -> key=tid>>2, dims (tid&3)*16..+15 ----
        {
            int key = tid >> 2, d0 = (tid & 3) * 16;
            const float* kp = base + (long)(kt * KVBLK + key) * F_ + E_ + d0;
            float4 u0 = *(const float4*)(kp);
            float4 u1 = *(const float4*)(kp + 4);
            float4 u2 = *(const float4*)(kp + 8);
            float4 u3 = *(const float4*)(kp + 12);
            int ch0 = ((d0 >> 3)) ^ (key & 7);
            int ch1 = ((d0 >> 3) + 1) ^ (key & 7);
            *(bf16x8*)&K_lds[key * 64 + ch0 * 8] = pack2(u0, u1);
            *(bf16x8*)&K_lds[key * 64 + ch1 * 8] = pack2(u2, u3);
        }
        // ---- stage V transposed: thread -> dim=tid>>2, keys (tid&3)*16..+15 ----
        {
            int d = tid >> 2, kg = tid & 3;
            const float* vp = base + (long)(kt * KVBLK + kg * 16) * F_ + 2 * E_ + d;
            float vv[16];
#pragma unroll
            for (int i = 0; i < 16; ++i) vv[i] = vp[(long)i * F_];
            bf16x8 c0, c1;
#pragma unroll
            for (int i = 0; i < 8; ++i) { c0[i] = f2bf(vv[i]); c1[i] = f2bf(vv[i + 8]); }
            int ch0 = (kg * 2) ^ (d & 7);
            int ch1 = (kg * 2 + 1) ^ (d & 7);
            *(bf16x8*)&Vt_lds[d * 64 + ch0 * 8] = c0;
            *(bf16x8*)&Vt_lds[d * 64 + ch1 * 8] = c1;
        }
        __syncthreads();

        if (kt * KVBLK <= qt * QBLK + w * 32 + 31) {
#pragma unroll
            for (int mg = 0; mg < 2; ++mg) {
                const int base_mg = qt * QBLK + w * 32 + mg * 16;
                // S = Q K^T
                f32x4 s[4];
#pragma unroll
                for (int n = 0; n < 4; ++n) {
                    bf16x8 kf0 = *(const bf16x8*)&K_lds[(16 * n + lr) * 64 + ((0 + lg) ^ (lr & 7)) * 8];
                    bf16x8 kf1 = *(const bf16x8*)&K_lds[(16 * n + lr) * 64 + ((4 + lg) ^ (lr & 7)) * 8];
                    f32x4 z = zero;
                    z = __builtin_amdgcn_mfma_f32_16x16x32_bf16(qf[mg][0], kf0, z, 0, 0, 0);
                    z = __builtin_amdgcn_mfma_f32_16x16x32_bf16(qf[mg][1], kf1, z, 0, 0, 0);
                    s[n] = z;
                }
                // causal mask
                if (kt * KVBLK + 63 > base_mg) {
#pragma unroll
                    for (int n = 0; n < 4; ++n)
#pragma unroll
                        for (int r = 0; r < 4; ++r) {
                            int key = kt * KVBLK + 16 * n + lr;
                            int qr = base_mg + 4 * lg + r;
                            if (key > qr) s[n][r] = -1e30f;
                        }
                }
                // online softmax
                float alpha[4];
#pragma unroll
                for (int r = 0; r < 4; ++r) {
                    float t = fmaxf(fmaxf(s[0][r], s[1][r]), fmaxf(s[2][r], s[3][r]));
                    t = fmaxf(t, __shfl_xor(t, 1, 64));
                    t = fmaxf(t, __shfl_xor(t, 2, 64));
                    t = fmaxf(t, __shfl_xor(t, 4, 64));
                    t = fmaxf(t, __shfl_xor(t, 8, 64));
                    float mn = fmaxf(mrow[mg][r], t);
                    float al = __expf(mrow[mg][r] - mn);
                    mrow[mg][r] = mn;
                    float ps = 0.f;
#pragma unroll
                    for (int n = 0; n < 4; ++n) {
                        float p = __expf(s[n][r] - mn);
                        s[n][r] = p;
                        ps += p;
                    }
                    ps += __shfl_xor(ps, 1, 64);
                    ps += __shfl_xor(ps, 2, 64);
                    ps += __shfl_xor(ps, 4, 64);
                    ps += __shfl_xor(ps, 8, 64);
                    lrow[mg][r] = lrow[mg][r] * al + ps;
                    alpha[r] = al;
                }
#pragma unroll
                for (int n = 0; n < 4; ++n)
#pragma unroll
                    for (int r = 0; r < 4; ++r) o[mg][n][r] *= alpha[r];
                // P -> LDS (bf16, swizzled)
#pragma unroll
                for (int n = 0; n < 4; ++n)
#pragma unroll
                    for (int r = 0; r < 4; ++r) {
                        int row = mg * 16 + 4 * lg + r;
                        int col = 16 * n + lr;
                        int ch = (col >> 3) ^ (row & 7);
                        P_lds[w][row * 64 + ch * 8 + (col & 7)] = f2bf(s[n][r]);
                    }
                // PV
                int prow = mg * 16 + lr;
                bf16x8 pf[2];
#pragma unroll
                for (int kk = 0; kk < 2; ++kk)
                    pf[kk] = *(const bf16x8*)&P_lds[w][prow * 64 + ((kk * 4 + lg) ^ (lr & 7)) * 8];
#pragma unroll
                for (int n = 0; n < 4; ++n) {
                    bf16x8 vf0 = *(const bf16x8*)&Vt_lds[(16 * n + lr) * 64 + ((0 + lg) ^ (lr & 7)) * 8];
                    bf16x8 vf1 = *(const bf16x8*)&Vt_lds[(16 * n + lr) * 64 + ((4 + lg) ^ (lr & 7)) * 8];
                    o[mg][n] = __builtin_amdgcn_mfma_f32_16x16x32_bf16(pf[0], vf0, o[mg][n], 0, 0, 0);
                    o[mg][n] = __builtin_amdgcn_mfma_f32_16x16x32_bf16(pf[1], vf1, o[mg][n], 0, 0, 0);
                }
            }
        }
    }

    // epilogue
#pragma unroll
    for (int mg = 0; mg < 2; ++mg) {
        float inv[4];
#pragma unroll
        for (int r = 0; r < 4; ++r) inv[r] = 1.f / lrow[mg][r];
#pragma unroll
        for (int n = 0; n < 4; ++n)
#pragma unroll
            for (int r = 0; r < 4; ++r) {
                int qrow = qt * QBLK + w * 32 + mg * 16 + 4 * lg + r;
                out[((long)b * T_ + qrow) * E_ + h * HS_ + 16 * n + lr] = o[mg][n][r] * inv[r];
            }
    }
}

extern "C" void kernel_launch(void* const* d_in, const int* in_sizes, int n_in,
                              void* d_out, int out_size, void* d_ws, size_t ws_size,
                              hipStream_t stream) {
    const float* x     = (const float*)d_in[0];   // [4,2048,1024]
    const float* W_qkv = (const float*)d_in[1];   // [3072,1024]
    const float* b_qkv = (const float*)d_in[2];   // [3072]
    float* out = (float*)d_out;                   // [4,2048,1024]
    float* qkv = (float*)d_ws;                    // [8192,3072] fp32 = 96 MB

    dim3 ggrid(F_ / 128, M_ / 128);  // (24, 64)
    qkv_gemm_mfma<<<ggrid, 256, 0, stream>>>(x, W_qkv, b_qkv, qkv);

    dim3 agrid(T_ / QBLK, B_ * NH_);  // (16, 64)
    attn_mfma<<<agrid, 256, 0, stream>>>(qkv, out);
}

// Round 3
// 350.933 us; speedup vs baseline: 28.3462x; 1.3310x over previous
//
#include <hip/hip_runtime.h>
#include <hip/hip_bf16.h>

#define B_   4
#define T_   2048
#define E_   1024
#define NH_  16
#define HS_  64
#define F_   (3 * E_)   // 3072
#define M_   (B_ * T_)  // 8192

typedef short bf16x8 __attribute__((ext_vector_type(8)));
typedef float f32x4 __attribute__((ext_vector_type(4)));

__device__ __forceinline__ short f2bf(float f) {
    __hip_bfloat16 h = __float2bfloat16(f);
    return *reinterpret_cast<short*>(&h);
}

__device__ __forceinline__ bf16x8 pack2(float4 a, float4 b) {
    bf16x8 r;
    r[0] = f2bf(a.x); r[1] = f2bf(a.y); r[2] = f2bf(a.z); r[3] = f2bf(a.w);
    r[4] = f2bf(b.x); r[5] = f2bf(b.y); r[6] = f2bf(b.z); r[7] = f2bf(b.w);
    return r;
}

// ---------------- QKV GEMM: bf16 MFMA, epilogue writes bf16 Q/K/Vt buffers ----------------
__global__ __launch_bounds__(256) void qkv_gemm_mfma(const float* __restrict__ X,
                                                     const float* __restrict__ Wq,
                                                     const float* __restrict__ bias,
                                                     __hip_bfloat16* __restrict__ Qb,
                                                     __hip_bfloat16* __restrict__ Kb,
                                                     __hip_bfloat16* __restrict__ Vt) {
    __shared__ __align__(16) short A_lds[128 * 64];
    __shared__ __align__(16) short B_lds[128 * 64];
    const int tid = threadIdx.x;
    const int w = tid >> 6, l = tid & 63, lg = l >> 4, lr = l & 15;
    const int wm = w >> 1, wn = w & 1;
    const int bm = blockIdx.y, bn = blockIdx.x;

    const f32x4 zero = {0.f, 0.f, 0.f, 0.f};
    f32x4 acc[4][4];
#pragma unroll
    for (int i = 0; i < 4; ++i)
#pragma unroll
        for (int j = 0; j < 4; ++j) acc[i][j] = zero;

    const int srow = tid >> 1, sd0 = (tid & 1) * 32;
    const float* xp = X + (long)(bm * 128 + srow) * E_ + sd0;
    const float* wp = Wq + (long)(bn * 128 + srow) * E_ + sd0;

    for (int k0 = 0; k0 < E_; k0 += 64) {
        __syncthreads();
#pragma unroll
        for (int c = 0; c < 4; ++c) {
            float4 u0 = *(const float4*)(xp + k0 + c * 8);
            float4 u1 = *(const float4*)(xp + k0 + c * 8 + 4);
            int ch = ((sd0 >> 3) + c) ^ (srow & 7);
            *(bf16x8*)&A_lds[srow * 64 + ch * 8] = pack2(u0, u1);
        }
#pragma unroll
        for (int c = 0; c < 4; ++c) {
            float4 u0 = *(const float4*)(wp + k0 + c * 8);
            float4 u1 = *(const float4*)(wp + k0 + c * 8 + 4);
            int ch = ((sd0 >> 3) + c) ^ (srow & 7);
            *(bf16x8*)&B_lds[srow * 64 + ch * 8] = pack2(u0, u1);
        }
        __syncthreads();

        bf16x8 af[4][2], bfr[4][2];
#pragma unroll
        for (int mg = 0; mg < 4; ++mg)
#pragma unroll
            for (int kk = 0; kk < 2; ++kk)
                af[mg][kk] = *(const bf16x8*)&A_lds[(wm * 64 + mg * 16 + lr) * 64 + ((kk * 4 + lg) ^ (lr & 7)) * 8];
#pragma unroll
        for (int ng = 0; ng < 4; ++ng)
#pragma unroll
            for (int kk = 0; kk < 2; ++kk)
                bfr[ng][kk] = *(const bf16x8*)&B_lds[(wn * 64 + ng * 16 + lr) * 64 + ((kk * 4 + lg) ^ (lr & 7)) * 8];

#pragma unroll
        for (int mg = 0; mg < 4; ++mg)
#pragma unroll
            for (int ng = 0; ng < 4; ++ng) {
                acc[mg][ng] = __builtin_amdgcn_mfma_f32_16x16x32_bf16(af[mg][0], bfr[ng][0], acc[mg][ng], 0, 0, 0);
                acc[mg][ng] = __builtin_amdgcn_mfma_f32_16x16x32_bf16(af[mg][1], bfr[ng][1], acc[mg][ng], 0, 0, 0);
            }
    }

    // epilogue: section (q/k/v) is uniform per block: bn in [0,8) q, [8,16) k, [16,24) v
    const int sec = bn >> 3;
#pragma unroll
    for (int mg = 0; mg < 4; ++mg)
#pragma unroll
        for (int ng = 0; ng < 4; ++ng)
#pragma unroll
            for (int r = 0; r < 4; ++r) {
                int row = bm * 128 + wm * 64 + mg * 16 + 4 * lg + r;  // 0..8191
                int col = bn * 128 + wn * 64 + ng * 16 + lr;          // 0..3071
                int cl = col & 1023;
                int h = cl >> 6, d = cl & 63;
                int b = row >> 11, t = row & 2047;
                int bh = b * 16 + h;
                float v = acc[mg][ng][r] + bias[col];
                if (sec == 0)
                    Qb[((long)bh * T_ + t) * 64 + d] = __float2bfloat16(v * 0.125f);
                else if (sec == 1)
                    Kb[((long)bh * T_ + t) * 64 + d] = __float2bfloat16(v);
                else
                    Vt[((long)bh * 64 + d) * T_ + t] = __float2bfloat16(v);
            }
}

// ---------------- Flash attention: paired q-tiles (p, 15-p), shared KV staging ----------------
__global__ __launch_bounds__(256, 2) void attn_mfma(const __hip_bfloat16* __restrict__ Qb,
                                                    const __hip_bfloat16* __restrict__ Kb,
                                                    const __hip_bfloat16* __restrict__ Vt,
                                                    float* __restrict__ out) {
    const int p = blockIdx.x;       // 0..7
    const int bh = blockIdx.y;      // 0..63
    const int b = bh >> 4, h = bh & 15;
    const int tid = threadIdx.x;
    const int w = tid >> 6, l = tid & 63, lg = l >> 4, lr = l & 15;

    __shared__ __align__(16) short K_lds[64 * 64];    // [key][dim] swizzled
    __shared__ __align__(16) short Vt_lds[64 * 64];   // [dim][key] swizzled
    __shared__ __align__(16) short P_lds[4][32 * 64]; // per-wave [row][key] swizzled

    const int qt[2] = {p, 15 - p};
    const short* qbase = (const short*)Qb + (long)bh * T_ * 64;
    const short* kbase = (const short*)Kb + (long)bh * T_ * 64;
    const short* vbase = (const short*)Vt + (long)bh * 64 * T_;

    // Q fragments (already scaled by 1/8 at GEMM epilogue)
    bf16x8 qf[2][2][2];
#pragma unroll
    for (int ti = 0; ti < 2; ++ti)
#pragma unroll
        for (int mg = 0; mg < 2; ++mg) {
            int qrow = qt[ti] * 128 + w * 32 + mg * 16 + lr;
#pragma unroll
            for (int kk = 0; kk < 2; ++kk)
                qf[ti][mg][kk] = *(const bf16x8*)&qbase[(long)qrow * 64 + kk * 32 + lg * 8];
        }

    const f32x4 zero = {0.f, 0.f, 0.f, 0.f};
    f32x4 o[2][2][4];
    float mrow[2][2][4], lrow[2][2][4];
#pragma unroll
    for (int ti = 0; ti < 2; ++ti)
#pragma unroll
        for (int mg = 0; mg < 2; ++mg) {
#pragma unroll
            for (int r = 0; r < 4; ++r) { mrow[ti][mg][r] = -1e30f; lrow[ti][mg][r] = 0.f; }
#pragma unroll
            for (int n = 0; n < 4; ++n) o[ti][mg][n] = zero;
        }

    const int nkt = 2 * qt[1] + 2;  // qt[1] is the larger tile
    for (int kt = 0; kt < nkt; ++kt) {
        __syncthreads();
        // stage K: thread -> key=tid>>2, chunks (tid&3)*2, +1 (each chunk = 8 bf16)
        {
            int key = tid >> 2, c0 = (tid & 3) * 2;
            const short* kp = &kbase[(long)(kt * 64 + key) * 64 + c0 * 8];
            bf16x8 u0 = *(const bf16x8*)kp;
            bf16x8 u1 = *(const bf16x8*)(kp + 8);
            *(bf16x8*)&K_lds[key * 64 + ((c0    ) ^ (key & 7)) * 8] = u0;
            *(bf16x8*)&K_lds[key * 64 + ((c0 + 1) ^ (key & 7)) * 8] = u1;
        }
        // stage Vt: thread -> dim=tid>>2, key-chunks (tid&3)*2, +1
        {
            int d = tid >> 2, c0 = (tid & 3) * 2;
            const short* vp = &vbase[(long)d * T_ + kt * 64 + c0 * 8];
            bf16x8 u0 = *(const bf16x8*)vp;
            bf16x8 u1 = *(const bf16x8*)(vp + 8);
            *(bf16x8*)&Vt_lds[d * 64 + ((c0    ) ^ (d & 7)) * 8] = u0;
            *(bf16x8*)&Vt_lds[d * 64 + ((c0 + 1) ^ (d & 7)) * 8] = u1;
        }
        __syncthreads();

#pragma unroll
        for (int ti = 0; ti < 2; ++ti) {
            const int wbase = qt[ti] * 128 + w * 32;
            if (kt * 64 > wbase + 31) continue;  // fully masked for this wave's rows
#pragma unroll
            for (int mg = 0; mg < 2; ++mg) {
                const int base_mg = wbase + mg * 16;
                // S = Q K^T
                f32x4 s[4];
#pragma unroll
                for (int n = 0; n < 4; ++n) {
                    bf16x8 kf0 = *(const bf16x8*)&K_lds[(16 * n + lr) * 64 + ((0 + lg) ^ (lr & 7)) * 8];
                    bf16x8 kf1 = *(const bf16x8*)&K_lds[(16 * n + lr) * 64 + ((4 + lg) ^ (lr & 7)) * 8];
                    f32x4 z = zero;
                    z = __builtin_amdgcn_mfma_f32_16x16x32_bf16(qf[ti][mg][0], kf0, z, 0, 0, 0);
                    z = __builtin_amdgcn_mfma_f32_16x16x32_bf16(qf[ti][mg][1], kf1, z, 0, 0, 0);
                    s[n] = z;
                }
                // causal mask
                if (kt * 64 + 63 > base_mg) {
#pragma unroll
                    for (int n = 0; n < 4; ++n)
#pragma unroll
                        for (int r = 0; r < 4; ++r) {
                            int key = kt * 64 + 16 * n + lr;
                            int qr = base_mg + 4 * lg + r;
                            if (key > qr) s[n][r] = -1e30f;
                        }
                }
                // online softmax
                float alpha[4];
#pragma unroll
                for (int r = 0; r < 4; ++r) {
                    float t = fmaxf(fmaxf(s[0][r], s[1][r]), fmaxf(s[2][r], s[3][r]));
                    t = fmaxf(t, __shfl_xor(t, 1, 64));
                    t = fmaxf(t, __shfl_xor(t, 2, 64));
                    t = fmaxf(t, __shfl_xor(t, 4, 64));
                    t = fmaxf(t, __shfl_xor(t, 8, 64));
                    float mn = fmaxf(mrow[ti][mg][r], t);
                    float al = __expf(mrow[ti][mg][r] - mn);
                    mrow[ti][mg][r] = mn;
                    float ps = 0.f;
#pragma unroll
                    for (int n = 0; n < 4; ++n) {
                        float pv = __expf(s[n][r] - mn);
                        s[n][r] = pv;
                        ps += pv;
                    }
                    ps += __shfl_xor(ps, 1, 64);
                    ps += __shfl_xor(ps, 2, 64);
                    ps += __shfl_xor(ps, 4, 64);
                    ps += __shfl_xor(ps, 8, 64);
                    lrow[ti][mg][r] = lrow[ti][mg][r] * al + ps;
                    alpha[r] = al;
                }
#pragma unroll
                for (int n = 0; n < 4; ++n)
#pragma unroll
                    for (int r = 0; r < 4; ++r) o[ti][mg][n][r] *= alpha[r];
                // P -> LDS (bf16, swizzled)
#pragma unroll
                for (int n = 0; n < 4; ++n)
#pragma unroll
                    for (int r = 0; r < 4; ++r) {
                        int row = mg * 16 + 4 * lg + r;
                        int col = 16 * n + lr;
                        int ch = (col >> 3) ^ (row & 7);
                        P_lds[w][row * 64 + ch * 8 + (col & 7)] = f2bf(s[n][r]);
                    }
                // PV
                int prow = mg * 16 + lr;
                bf16x8 pf[2];
#pragma unroll
                for (int kk = 0; kk < 2; ++kk)
                    pf[kk] = *(const bf16x8*)&P_lds[w][prow * 64 + ((kk * 4 + lg) ^ (lr & 7)) * 8];
#pragma unroll
                for (int n = 0; n < 4; ++n) {
                    bf16x8 vf0 = *(const bf16x8*)&Vt_lds[(16 * n + lr) * 64 + ((0 + lg) ^ (lr & 7)) * 8];
                    bf16x8 vf1 = *(const bf16x8*)&Vt_lds[(16 * n + lr) * 64 + ((4 + lg) ^ (lr & 7)) * 8];
                    o[ti][mg][n] = __builtin_amdgcn_mfma_f32_16x16x32_bf16(pf[0], vf0, o[ti][mg][n], 0, 0, 0);
                    o[ti][mg][n] = __builtin_amdgcn_mfma_f32_16x16x32_bf16(pf[1], vf1, o[ti][mg][n], 0, 0, 0);
                }
            }
        }
    }

    // epilogue
#pragma unroll
    for (int ti = 0; ti < 2; ++ti)
#pragma unroll
        for (int mg = 0; mg < 2; ++mg) {
            float inv[4];
#pragma unroll
            for (int r = 0; r < 4; ++r) inv[r] = 1.f / lrow[ti][mg][r];
#pragma unroll
            for (int n = 0; n < 4; ++n)
#pragma unroll
                for (int r = 0; r < 4; ++r) {
                    int qrow = qt[ti] * 128 + w * 32 + mg * 16 + 4 * lg + r;
                    out[((long)b * T_ + qrow) * E_ + h * HS_ + 16 * n + lr] = o[ti][mg][n][r] * inv[r];
                }
        }
}

extern "C" void kernel_launch(void* const* d_in, const int* in_sizes, int n_in,
                              void* d_out, int out_size, void* d_ws, size_t ws_size,
                              hipStream_t stream) {
    const float* x     = (const float*)d_in[0];   // [4,2048,1024]
    const float* W_qkv = (const float*)d_in[1];   // [3072,1024]
    const float* b_qkv = (const float*)d_in[2];   // [3072]
    float* out = (float*)d_out;                   // [4,2048,1024]

    const long per = (long)64 * T_ * 64;          // 8.4M elems per buffer
    __hip_bfloat16* Qb = (__hip_bfloat16*)d_ws;
    __hip_bfloat16* Kb = Qb + per;
    __hip_bfloat16* Vt = Kb + per;

    dim3 ggrid(F_ / 128, M_ / 128);  // (24, 64)
    qkv_gemm_mfma<<<ggrid, 256, 0, stream>>>(x, W_qkv, b_qkv, Qb, Kb, Vt);

    dim3 agrid(8, B_ * NH_);  // (8, 64)
    attn_mfma<<<agrid, 256, 0, stream>>>(Qb, Kb, Vt, out);
}

// Round 4
// 232.900 us; speedup vs baseline: 42.7120x; 1.5068x over previous
//
#include <hip/hip_runtime.h>
#include <hip/hip_bf16.h>

#define B_   4
#define T_   2048
#define E_   1024
#define NH_  16
#define HS_  64
#define F_   (3 * E_)   // 3072
#define M_   (B_ * T_)  // 8192

typedef short bf16x8 __attribute__((ext_vector_type(8)));
typedef float f32x4 __attribute__((ext_vector_type(4)));

__device__ __forceinline__ short f2bf(float f) {
    __hip_bfloat16 h = __float2bfloat16(f);
    return *reinterpret_cast<short*>(&h);
}

__device__ __forceinline__ bf16x8 pack2(float4 a, float4 b) {
    bf16x8 r;
    r[0] = f2bf(a.x); r[1] = f2bf(a.y); r[2] = f2bf(a.z); r[3] = f2bf(a.w);
    r[4] = f2bf(b.x); r[5] = f2bf(b.y); r[6] = f2bf(b.z); r[7] = f2bf(b.w);
    return r;
}

__device__ __forceinline__ void gload16(const void* g, void* l) {
    __builtin_amdgcn_global_load_lds(
        (const __attribute__((address_space(1))) unsigned int*)g,
        (__attribute__((address_space(3))) unsigned int*)l, 16, 0, 0);
}

// ---------------- fp32 -> bf16 pre-pass for X and W ----------------
__global__ __launch_bounds__(256) void cvt_bf16(const float* __restrict__ X,
                                                const float* __restrict__ W,
                                                short* __restrict__ Xb,
                                                short* __restrict__ Wb) {
    const long nX = (long)M_ * E_;   // 8388608
    long i = ((long)blockIdx.x * 256 + threadIdx.x) * 8;
    const float* src;
    short* dst;
    long off;
    if (i < nX) { src = X; dst = Xb; off = i; }
    else        { src = W; dst = Wb; off = i - nX; }
    float4 a = *(const float4*)(src + off);
    float4 b = *(const float4*)(src + off + 4);
    *(bf16x8*)(dst + off) = pack2(a, b);
}

// ---------------- QKV GEMM: m97 structure (global_load_lds, linear LDS) ----------------
__global__ __launch_bounds__(256) void qkv_gemm_mfma(const short* __restrict__ Xb,
                                                     const short* __restrict__ Wb,
                                                     const float* __restrict__ bias,
                                                     __hip_bfloat16* __restrict__ Qb,
                                                     __hip_bfloat16* __restrict__ Kb,
                                                     __hip_bfloat16* __restrict__ Vt) {
    __shared__ __align__(16) short A_lds[128 * 64];
    __shared__ __align__(16) short B_lds[128 * 64];
    const int tid = threadIdx.x;
    const int w = tid >> 6, l = tid & 63, lg = l >> 4, lr = l & 15;
    const int wm = w >> 1, wn = w & 1;

    // bijective XCD swizzle: 1536 blocks, 8 XCDs, 192 blocks each
    const int bid = blockIdx.x;
    const int sw = (bid & 7) * 192 + (bid >> 3);
    const int bm = sw / 24, bn = sw % 24;

    const f32x4 zero = {0.f, 0.f, 0.f, 0.f};
    f32x4 acc[4][4];
#pragma unroll
    for (int i = 0; i < 4; ++i)
#pragma unroll
        for (int j = 0; j < 4; ++j) acc[i][j] = zero;

    // staging: wave w covers rows [w*32, w*32+32) of each tile; instr i = 8 rows;
    // lane l -> row_local = i*8 + (l>>3), elems (l&7)*8 .. +7  (16 B)
    const short* ga = Xb + ((long)(bm * 128 + w * 32) + (l >> 3)) * E_ + (l & 7) * 8;
    const short* gb = Wb + ((long)(bn * 128 + w * 32) + (l >> 3)) * E_ + (l & 7) * 8;
    short* la = A_lds + (w * 32) * 64;
    short* lb = B_lds + (w * 32) * 64;

    for (int k0 = 0; k0 < E_; k0 += 64) {
        __syncthreads();
#pragma unroll
        for (int i = 0; i < 4; ++i) {
            gload16(ga + (long)i * 8 * E_ + k0, la + i * 8 * 64);
            gload16(gb + (long)i * 8 * E_ + k0, lb + i * 8 * 64);
        }
        __syncthreads();

        bf16x8 af[4][2], bfr[4][2];
#pragma unroll
        for (int mg = 0; mg < 4; ++mg)
#pragma unroll
            for (int kk = 0; kk < 2; ++kk)
                af[mg][kk] = *(const bf16x8*)&A_lds[(wm * 64 + mg * 16 + lr) * 64 + kk * 32 + lg * 8];
#pragma unroll
        for (int ng = 0; ng < 4; ++ng)
#pragma unroll
            for (int kk = 0; kk < 2; ++kk)
                bfr[ng][kk] = *(const bf16x8*)&B_lds[(wn * 64 + ng * 16 + lr) * 64 + kk * 32 + lg * 8];

#pragma unroll
        for (int mg = 0; mg < 4; ++mg)
#pragma unroll
            for (int ng = 0; ng < 4; ++ng) {
                acc[mg][ng] = __builtin_amdgcn_mfma_f32_16x16x32_bf16(af[mg][0], bfr[ng][0], acc[mg][ng], 0, 0, 0);
                acc[mg][ng] = __builtin_amdgcn_mfma_f32_16x16x32_bf16(af[mg][1], bfr[ng][1], acc[mg][ng], 0, 0, 0);
            }
    }

    // epilogue: section (q/k/v) uniform per block: bn in [0,8) q, [8,16) k, [16,24) v
    const int sec = bn >> 3;
#pragma unroll
    for (int mg = 0; mg < 4; ++mg)
#pragma unroll
        for (int ng = 0; ng < 4; ++ng)
#pragma unroll
            for (int r = 0; r < 4; ++r) {
                int row = bm * 128 + wm * 64 + mg * 16 + 4 * lg + r;  // 0..8191
                int col = bn * 128 + wn * 64 + ng * 16 + lr;          // 0..3071
                int cl = col & 1023;
                int h = cl >> 6, d = cl & 63;
                int b = row >> 11, t = row & 2047;
                int bh = b * 16 + h;
                float v = acc[mg][ng][r] + bias[col];
                if (sec == 0)
                    Qb[((long)bh * T_ + t) * 64 + d] = __float2bfloat16(v * 0.125f);
                else if (sec == 1)
                    Kb[((long)bh * T_ + t) * 64 + d] = __float2bfloat16(v);
                else
                    Vt[((long)bh * 64 + d) * T_ + t] = __float2bfloat16(v);
            }
}

// ---------------- Flash attention: paired q-tiles (p, 15-p), shared KV staging ----------------
__global__ __launch_bounds__(256, 2) void attn_mfma(const __hip_bfloat16* __restrict__ Qb,
                                                    const __hip_bfloat16* __restrict__ Kb,
                                                    const __hip_bfloat16* __restrict__ Vt,
                                                    float* __restrict__ out) {
    const int p = blockIdx.x;       // 0..7
    const int bh = blockIdx.y;      // 0..63
    const int b = bh >> 4, h = bh & 15;
    const int tid = threadIdx.x;
    const int w = tid >> 6, l = tid & 63, lg = l >> 4, lr = l & 15;

    __shared__ __align__(16) short K_lds[64 * 64];    // [key][dim] swizzled
    __shared__ __align__(16) short Vt_lds[64 * 64];   // [dim][key] swizzled
    __shared__ __align__(16) short P_lds[4][32 * 64]; // per-wave [row][key] swizzled

    const int qt[2] = {p, 15 - p};
    const short* qbase = (const short*)Qb + (long)bh * T_ * 64;
    const short* kbase = (const short*)Kb + (long)bh * T_ * 64;
    const short* vbase = (const short*)Vt + (long)bh * 64 * T_;

    // Q fragments (already scaled by 1/8 at GEMM epilogue)
    bf16x8 qf[2][2][2];
#pragma unroll
    for (int ti = 0; ti < 2; ++ti)
#pragma unroll
        for (int mg = 0; mg < 2; ++mg) {
            int qrow = qt[ti] * 128 + w * 32 + mg * 16 + lr;
#pragma unroll
            for (int kk = 0; kk < 2; ++kk)
                qf[ti][mg][kk] = *(const bf16x8*)&qbase[(long)qrow * 64 + kk * 32 + lg * 8];
        }

    const f32x4 zero = {0.f, 0.f, 0.f, 0.f};
    f32x4 o[2][2][4];
    float mrow[2][2][4], lrow[2][2][4];
#pragma unroll
    for (int ti = 0; ti < 2; ++ti)
#pragma unroll
        for (int mg = 0; mg < 2; ++mg) {
#pragma unroll
            for (int r = 0; r < 4; ++r) { mrow[ti][mg][r] = -1e30f; lrow[ti][mg][r] = 0.f; }
#pragma unroll
            for (int n = 0; n < 4; ++n) o[ti][mg][n] = zero;
        }

    const int nkt = 2 * qt[1] + 2;  // qt[1] is the larger tile
    for (int kt = 0; kt < nkt; ++kt) {
        __syncthreads();
        // stage K: thread -> key=tid>>2, chunks (tid&3)*2, +1 (each chunk = 8 bf16)
        {
            int key = tid >> 2, c0 = (tid & 3) * 2;
            const short* kp = &kbase[(long)(kt * 64 + key) * 64 + c0 * 8];
            bf16x8 u0 = *(const bf16x8*)kp;
            bf16x8 u1 = *(const bf16x8*)(kp + 8);
            *(bf16x8*)&K_lds[key * 64 + ((c0    ) ^ (key & 7)) * 8] = u0;
            *(bf16x8*)&K_lds[key * 64 + ((c0 + 1) ^ (key & 7)) * 8] = u1;
        }
        // stage Vt: thread -> dim=tid>>2, key-chunks (tid&3)*2, +1
        {
            int d = tid >> 2, c0 = (tid & 3) * 2;
            const short* vp = &vbase[(long)d * T_ + kt * 64 + c0 * 8];
            bf16x8 u0 = *(const bf16x8*)vp;
            bf16x8 u1 = *(const bf16x8*)(vp + 8);
            *(bf16x8*)&Vt_lds[d * 64 + ((c0    ) ^ (d & 7)) * 8] = u0;
            *(bf16x8*)&Vt_lds[d * 64 + ((c0 + 1) ^ (d & 7)) * 8] = u1;
        }
        __syncthreads();

#pragma unroll
        for (int ti = 0; ti < 2; ++ti) {
            const int wbase = qt[ti] * 128 + w * 32;
            if (kt * 64 > wbase + 31) continue;  // fully masked for this wave's rows
#pragma unroll
            for (int mg = 0; mg < 2; ++mg) {
                const int base_mg = wbase + mg * 16;
                // S = Q K^T
                f32x4 s[4];
#pragma unroll
                for (int n = 0; n < 4; ++n) {
                    bf16x8 kf0 = *(const bf16x8*)&K_lds[(16 * n + lr) * 64 + ((0 + lg) ^ (lr & 7)) * 8];
                    bf16x8 kf1 = *(const bf16x8*)&K_lds[(16 * n + lr) * 64 + ((4 + lg) ^ (lr & 7)) * 8];
                    f32x4 z = zero;
                    z = __builtin_amdgcn_mfma_f32_16x16x32_bf16(qf[ti][mg][0], kf0, z, 0, 0, 0);
                    z = __builtin_amdgcn_mfma_f32_16x16x32_bf16(qf[ti][mg][1], kf1, z, 0, 0, 0);
                    s[n] = z;
                }
                // causal mask
                if (kt * 64 + 63 > base_mg) {
#pragma unroll
                    for (int n = 0; n < 4; ++n)
#pragma unroll
                        for (int r = 0; r < 4; ++r) {
                            int key = kt * 64 + 16 * n + lr;
                            int qr = base_mg + 4 * lg + r;
                            if (key > qr) s[n][r] = -1e30f;
                        }
                }
                // online softmax
                float alpha[4];
#pragma unroll
                for (int r = 0; r < 4; ++r) {
                    float t = fmaxf(fmaxf(s[0][r], s[1][r]), fmaxf(s[2][r], s[3][r]));
                    t = fmaxf(t, __shfl_xor(t, 1, 64));
                    t = fmaxf(t, __shfl_xor(t, 2, 64));
                    t = fmaxf(t, __shfl_xor(t, 4, 64));
                    t = fmaxf(t, __shfl_xor(t, 8, 64));
                    float mn = fmaxf(mrow[ti][mg][r], t);
                    float al = __expf(mrow[ti][mg][r] - mn);
                    mrow[ti][mg][r] = mn;
                    float ps = 0.f;
#pragma unroll
                    for (int n = 0; n < 4; ++n) {
                        float pv = __expf(s[n][r] - mn);
                        s[n][r] = pv;
                        ps += pv;
                    }
                    ps += __shfl_xor(ps, 1, 64);
                    ps += __shfl_xor(ps, 2, 64);
                    ps += __shfl_xor(ps, 4, 64);
                    ps += __shfl_xor(ps, 8, 64);
                    lrow[ti][mg][r] = lrow[ti][mg][r] * al + ps;
                    alpha[r] = al;
                }
#pragma unroll
                for (int n = 0; n < 4; ++n)
#pragma unroll
                    for (int r = 0; r < 4; ++r) o[ti][mg][n][r] *= alpha[r];
                // P -> LDS (bf16, swizzled)
#pragma unroll
                for (int n = 0; n < 4; ++n)
#pragma unroll
                    for (int r = 0; r < 4; ++r) {
                        int row = mg * 16 + 4 * lg + r;
                        int col = 16 * n + lr;
                        int ch = (col >> 3) ^ (row & 7);
                        P_lds[w][row * 64 + ch * 8 + (col & 7)] = f2bf(s[n][r]);
                    }
                // PV
                int prow = mg * 16 + lr;
                bf16x8 pf[2];
#pragma unroll
                for (int kk = 0; kk < 2; ++kk)
                    pf[kk] = *(const bf16x8*)&P_lds[w][prow * 64 + ((kk * 4 + lg) ^ (lr & 7)) * 8];
#pragma unroll
                for (int n = 0; n < 4; ++n) {
                    bf16x8 vf0 = *(const bf16x8*)&Vt_lds[(16 * n + lr) * 64 + ((0 + lg) ^ (lr & 7)) * 8];
                    bf16x8 vf1 = *(const bf16x8*)&Vt_lds[(16 * n + lr) * 64 + ((4 + lg) ^ (lr & 7)) * 8];
                    o[ti][mg][n] = __builtin_amdgcn_mfma_f32_16x16x32_bf16(pf[0], vf0, o[ti][mg][n], 0, 0, 0);
                    o[ti][mg][n] = __builtin_amdgcn_mfma_f32_16x16x32_bf16(pf[1], vf1, o[ti][mg][n], 0, 0, 0);
                }
            }
        }
    }

    // epilogue
#pragma unroll
    for (int ti = 0; ti < 2; ++ti)
#pragma unroll
        for (int mg = 0; mg < 2; ++mg) {
            float inv[4];
#pragma unroll
            for (int r = 0; r < 4; ++r) inv[r] = 1.f / lrow[ti][mg][r];
#pragma unroll
            for (int n = 0; n < 4; ++n)
#pragma unroll
                for (int r = 0; r < 4; ++r) {
                    int qrow = qt[ti] * 128 + w * 32 + mg * 16 + 4 * lg + r;
                    out[((long)b * T_ + qrow) * E_ + h * HS_ + 16 * n + lr] = o[ti][mg][n][r] * inv[r];
                }
        }
}

extern "C" void kernel_launch(void* const* d_in, const int* in_sizes, int n_in,
                              void* d_out, int out_size, void* d_ws, size_t ws_size,
                              hipStream_t stream) {
    const float* x     = (const float*)d_in[0];   // [4,2048,1024]
    const float* W_qkv = (const float*)d_in[1];   // [3072,1024]
    const float* b_qkv = (const float*)d_in[2];   // [3072]
    float* out = (float*)d_out;                   // [4,2048,1024]

    const long per = (long)64 * T_ * 64;          // 8,388,608 elems
    __hip_bfloat16* Qb = (__hip_bfloat16*)d_ws;
    __hip_bfloat16* Kb = Qb + per;
    __hip_bfloat16* Vt = Kb + per;
    short* Xb = (short*)(Vt + per);               // 8,388,608 elems
    short* Wb = Xb + (long)M_ * E_;               // 3,145,728 elems

    const long ncvt = ((long)M_ * E_ + (long)F_ * E_) / 8;  // 1,441,792 threads
    cvt_bf16<<<(int)(ncvt / 256), 256, 0, stream>>>(x, W_qkv, Xb, Wb);

    qkv_gemm_mfma<<<24 * 64, 256, 0, stream>>>(Xb, Wb, b_qkv, Qb, Kb, Vt);

    dim3 agrid(8, B_ * NH_);  // (8, 64)
    attn_mfma<<<agrid, 256, 0, stream>>>(Qb, Kb, Vt, out);
}

// Round 5
// 177.946 us; speedup vs baseline: 55.9025x; 1.3088x over previous
//
#include <hip/hip_runtime.h>
#include <hip/hip_bf16.h>

#define B_   4
#define T_   2048
#define E_   1024
#define NH_  16
#define HS_  64
#define F_   (3 * E_)   // 3072
#define M_   (B_ * T_)  // 8192

typedef short bf16x8 __attribute__((ext_vector_type(8)));
typedef float f32x4  __attribute__((ext_vector_type(4)));
typedef float f32x16 __attribute__((ext_vector_type(16)));

__device__ __forceinline__ short f2bf(float f) {
    __hip_bfloat16 h = __float2bfloat16(f);
    return *reinterpret_cast<short*>(&h);
}

__device__ __forceinline__ bf16x8 pack2(float4 a, float4 b) {
    bf16x8 r;
    r[0] = f2bf(a.x); r[1] = f2bf(a.y); r[2] = f2bf(a.z); r[3] = f2bf(a.w);
    r[4] = f2bf(b.x); r[5] = f2bf(b.y); r[6] = f2bf(b.z); r[7] = f2bf(b.w);
    return r;
}

__device__ __forceinline__ unsigned pkbf(float a, float b) {
    return ((unsigned)(unsigned short)f2bf(a)) | (((unsigned)(unsigned short)f2bf(b)) << 16);
}

__device__ __forceinline__ void gload16(const void* g, void* l) {
    __builtin_amdgcn_global_load_lds(
        (const __attribute__((address_space(1))) unsigned int*)g,
        (__attribute__((address_space(3))) unsigned int*)l, 16, 0, 0);
}

// ---------------- fp32 -> bf16 pre-pass for X and W ----------------
__global__ __launch_bounds__(256) void cvt_bf16(const float* __restrict__ X,
                                                const float* __restrict__ W,
                                                short* __restrict__ Xb,
                                                short* __restrict__ Wb) {
    const long nX = (long)M_ * E_;   // 8388608
    long i = ((long)blockIdx.x * 256 + threadIdx.x) * 8;
    const float* src;
    short* dst;
    long off;
    if (i < nX) { src = X; dst = Xb; off = i; }
    else        { src = W; dst = Wb; off = i - nX; }
    float4 a = *(const float4*)(src + off);
    float4 b = *(const float4*)(src + off + 4);
    *(bf16x8*)(dst + off) = pack2(a, b);
}

// ---------------- QKV GEMM: m97 structure (global_load_lds, linear LDS) ----------------
__global__ __launch_bounds__(256) void qkv_gemm_mfma(const short* __restrict__ Xb,
                                                     const short* __restrict__ Wb,
                                                     const float* __restrict__ bias,
                                                     __hip_bfloat16* __restrict__ Qb,
                                                     __hip_bfloat16* __restrict__ Kb,
                                                     __hip_bfloat16* __restrict__ Vt) {
    __shared__ __align__(16) short A_lds[128 * 64];
    __shared__ __align__(16) short B_lds[128 * 64];
    const int tid = threadIdx.x;
    const int w = tid >> 6, l = tid & 63, lg = l >> 4, lr = l & 15;
    const int wm = w >> 1, wn = w & 1;

    const int bid = blockIdx.x;
    const int sw = (bid & 7) * 192 + (bid >> 3);
    const int bm = sw / 24, bn = sw % 24;

    const f32x4 zero = {0.f, 0.f, 0.f, 0.f};
    f32x4 acc[4][4];
#pragma unroll
    for (int i = 0; i < 4; ++i)
#pragma unroll
        for (int j = 0; j < 4; ++j) acc[i][j] = zero;

    const short* ga = Xb + ((long)(bm * 128 + w * 32) + (l >> 3)) * E_ + (l & 7) * 8;
    const short* gb = Wb + ((long)(bn * 128 + w * 32) + (l >> 3)) * E_ + (l & 7) * 8;
    short* la = A_lds + (w * 32) * 64;
    short* lb = B_lds + (w * 32) * 64;

    for (int k0 = 0; k0 < E_; k0 += 64) {
        __syncthreads();
#pragma unroll
        for (int i = 0; i < 4; ++i) {
            gload16(ga + (long)i * 8 * E_ + k0, la + i * 8 * 64);
            gload16(gb + (long)i * 8 * E_ + k0, lb + i * 8 * 64);
        }
        __syncthreads();

        bf16x8 af[4][2], bfr[4][2];
#pragma unroll
        for (int mg = 0; mg < 4; ++mg)
#pragma unroll
            for (int kk = 0; kk < 2; ++kk)
                af[mg][kk] = *(const bf16x8*)&A_lds[(wm * 64 + mg * 16 + lr) * 64 + kk * 32 + lg * 8];
#pragma unroll
        for (int ng = 0; ng < 4; ++ng)
#pragma unroll
            for (int kk = 0; kk < 2; ++kk)
                bfr[ng][kk] = *(const bf16x8*)&B_lds[(wn * 64 + ng * 16 + lr) * 64 + kk * 32 + lg * 8];

#pragma unroll
        for (int mg = 0; mg < 4; ++mg)
#pragma unroll
            for (int ng = 0; ng < 4; ++ng) {
                acc[mg][ng] = __builtin_amdgcn_mfma_f32_16x16x32_bf16(af[mg][0], bfr[ng][0], acc[mg][ng], 0, 0, 0);
                acc[mg][ng] = __builtin_amdgcn_mfma_f32_16x16x32_bf16(af[mg][1], bfr[ng][1], acc[mg][ng], 0, 0, 0);
            }
    }

    const int sec = bn >> 3;
#pragma unroll
    for (int mg = 0; mg < 4; ++mg)
#pragma unroll
        for (int ng = 0; ng < 4; ++ng)
#pragma unroll
            for (int r = 0; r < 4; ++r) {
                int row = bm * 128 + wm * 64 + mg * 16 + 4 * lg + r;  // 0..8191
                int col = bn * 128 + wn * 64 + ng * 16 + lr;          // 0..3071
                int cl = col & 1023;
                int h = cl >> 6, d = cl & 63;
                int b = row >> 11, t = row & 2047;
                int bh = b * 16 + h;
                float v = acc[mg][ng][r] + bias[col];
                if (sec == 0)
                    Qb[((long)bh * T_ + t) * 64 + d] = __float2bfloat16(v * 0.125f);
                else if (sec == 1)
                    Kb[((long)bh * T_ + t) * 64 + d] = __float2bfloat16(v);
                else
                    Vt[((long)bh * 64 + d) * T_ + t] = __float2bfloat16(v);
            }
}

// ---------------- Flash attention v2: swapped QK^T, in-register softmax ----------------
// 1024 blocks, 4 waves x 32 q-rows. 32x32x16 MFMA. C/D map: col=lane&31,
// row=(reg&3)+8*(reg>>2)+4*(lane>>5). S^T=mfma(K,Q) -> lane owns q-col; O^T=mfma(Vt,P^T).
__global__ __launch_bounds__(256, 3) void attn_mfma2(const __hip_bfloat16* __restrict__ Qb,
                                                     const __hip_bfloat16* __restrict__ Kb,
                                                     const __hip_bfloat16* __restrict__ Vt,
                                                     float* __restrict__ out) {
    const int g = blockIdx.x;                 // 0..1023
    const int xcd = g & 7, kidx = g >> 3;     // 8 bh per XCD -> 4MB KV fits its L2
    const int bh = xcd * 8 + (kidx & 7);
    const int qt = 15 - (kidx >> 3);          // big tiles dispatch first
    const int b = bh >> 4, h = bh & 15;
    const int tid = threadIdx.x;
    const int wv = tid >> 6, ln = tid & 63;
    const int hi = ln >> 5, q5 = ln & 31;

    __shared__ __align__(16) short K_lds[64 * 64];   // [key][dim] swizzled
    __shared__ __align__(16) short Vt_lds[64 * 64];  // [dim][key] swizzled

    const short* qbase = (const short*)Qb + (long)bh * T_ * 64;
    const short* kbase = (const short*)Kb + (long)bh * T_ * 64;
    const short* vbase = (const short*)Vt + (long)bh * 64 * T_;

    const int wq0 = qt * 128 + wv * 32;
    const int qg = wq0 + q5;

    // Q as B-operand: B[col=q][k = w*16 + hi*8 + j]
    bf16x8 qf[4];
#pragma unroll
    for (int w = 0; w < 4; ++w)
        qf[w] = *(const bf16x8*)&qbase[(long)qg * 64 + w * 16 + hi * 8];

    const f32x16 zero16 = {0.f,0.f,0.f,0.f, 0.f,0.f,0.f,0.f, 0.f,0.f,0.f,0.f, 0.f,0.f,0.f,0.f};
    f32x16 o0 = zero16, o1 = zero16;   // O^T: dt=0 -> d 0..31, dt=1 -> d 32..63
    float mrun = -1e30f, lsum = 0.f;

    const int nkt = 2 * qt + 2;
    for (int kt = 0; kt < nkt; ++kt) {
        __syncthreads();
        // stage K: thread -> key=tid>>2, chunks (tid&3)*2, +1
        {
            int key = tid >> 2, c0 = (tid & 3) * 2;
            const short* kp = &kbase[(long)(kt * 64 + key) * 64 + c0 * 8];
            bf16x8 u0 = *(const bf16x8*)kp;
            bf16x8 u1 = *(const bf16x8*)(kp + 8);
            *(bf16x8*)&K_lds[key * 64 + ((c0    ) ^ (key & 7)) * 8] = u0;
            *(bf16x8*)&K_lds[key * 64 + ((c0 + 1) ^ (key & 7)) * 8] = u1;
        }
        // stage Vt: thread -> dim=tid>>2, key-chunks (tid&3)*2, +1
        {
            int d = tid >> 2, c0 = (tid & 3) * 2;
            const short* vp = &vbase[(long)d * T_ + kt * 64 + c0 * 8];
            bf16x8 u0 = *(const bf16x8*)vp;
            bf16x8 u1 = *(const bf16x8*)(vp + 8);
            *(bf16x8*)&Vt_lds[d * 64 + ((c0    ) ^ (d & 7)) * 8] = u0;
            *(bf16x8*)&Vt_lds[d * 64 + ((c0 + 1) ^ (d & 7)) * 8] = u1;
        }
        __syncthreads();

        if (kt * 64 > wq0 + 31) continue;                 // wave-uniform
        const bool act1 = (kt * 64 + 32) <= (wq0 + 31);   // subtile 1 active

        // ---- S^T = mfma(A=K, B=Q) per 32-key subtile ----
        f32x16 sa = zero16, sb = zero16;
#pragma unroll
        for (int w = 0; w < 4; ++w) {
            int key = q5;  // st=0 local row
            bf16x8 kf = *(const bf16x8*)&K_lds[key * 64 + (((w * 2 + hi)) ^ (key & 7)) * 8];
            sa = __builtin_amdgcn_mfma_f32_32x32x16_bf16(kf, qf[w], sa, 0, 0, 0);
        }
        if (act1) {
#pragma unroll
            for (int w = 0; w < 4; ++w) {
                int key = 32 + q5;
                bf16x8 kf = *(const bf16x8*)&K_lds[key * 64 + (((w * 2 + hi)) ^ (key & 7)) * 8];
                sb = __builtin_amdgcn_mfma_f32_32x32x16_bf16(kf, qf[w], sb, 0, 0, 0);
            }
        }

        // ---- causal mask (diagonal tiles only) ----
        if (kt * 64 + 31 > wq0) {
#pragma unroll
            for (int r = 0; r < 16; ++r) {
                int key = kt * 64 + (r & 3) + 8 * (r >> 2) + 4 * hi;
                sa[r] = (key <= qg) ? sa[r] : -1e30f;
            }
        }
        if (act1 && (kt * 64 + 63 > wq0)) {
#pragma unroll
            for (int r = 0; r < 16; ++r) {
                int key = kt * 64 + 32 + (r & 3) + 8 * (r >> 2) + 4 * hi;
                sb[r] = (key <= qg) ? sb[r] : -1e30f;
            }
        }

        // ---- online softmax: in-lane + one cross-half shuffle ----
        float tmax = sa[0];
#pragma unroll
        for (int r = 1; r < 16; ++r) tmax = fmaxf(tmax, sa[r]);
        if (act1) {
#pragma unroll
            for (int r = 0; r < 16; ++r) tmax = fmaxf(tmax, sb[r]);
        }
        tmax = fmaxf(tmax, __shfl_xor(tmax, 32, 64));
        const float mn = fmaxf(mrun, tmax);
        const float alpha = __expf(mrun - mn);
        mrun = mn;
        float rs = 0.f;
#pragma unroll
        for (int r = 0; r < 16; ++r) { sa[r] = __expf(sa[r] - mn); rs += sa[r]; }
        if (act1) {
#pragma unroll
            for (int r = 0; r < 16; ++r) { sb[r] = __expf(sb[r] - mn); rs += sb[r]; }
        }
        rs += __shfl_xor(rs, 32, 64);
        lsum = lsum * alpha + rs;
        o0 = o0 * alpha;
        o1 = o1 * alpha;

        // ---- PV: O^T += mfma(A=V^T, B=P^T), P assembled in-register ----
#pragma unroll
        for (int st = 0; st < 2; ++st) {
            if (st == 1 && !act1) break;
            const f32x16& s = (st == 0) ? sa : sb;
            unsigned pkv[8];
#pragma unroll
            for (int i = 0; i < 8; ++i) pkv[i] = pkbf(s[2 * i], s[2 * i + 1]);
#pragma unroll
            for (int ks = 0; ks < 2; ++ks) {
                unsigned x1 = (unsigned)__shfl_xor((int)(hi ? pkv[4 * ks]     : pkv[4 * ks + 2]), 32, 64);
                unsigned x2 = (unsigned)__shfl_xor((int)(hi ? pkv[4 * ks + 1] : pkv[4 * ks + 3]), 32, 64);
                union { unsigned u[4]; bf16x8 v; } fr;
                fr.u[0] = hi ? x1 : pkv[4 * ks];
                fr.u[1] = hi ? x2 : pkv[4 * ks + 1];
                fr.u[2] = hi ? pkv[4 * ks + 2] : x1;
                fr.u[3] = hi ? pkv[4 * ks + 3] : x2;
                // dt = 0: d rows 0..31 ; dt = 1: d rows 32..63
                {
                    int d = q5;
                    bf16x8 vf = *(const bf16x8*)&Vt_lds[d * 64 + ((st * 4 + ks * 2 + hi) ^ (d & 7)) * 8];
                    o0 = __builtin_amdgcn_mfma_f32_32x32x16_bf16(vf, fr.v, o0, 0, 0, 0);
                }
                {
                    int d = 32 + q5;
                    bf16x8 vf = *(const bf16x8*)&Vt_lds[d * 64 + ((st * 4 + ks * 2 + hi) ^ (d & 7)) * 8];
                    o1 = __builtin_amdgcn_mfma_f32_32x32x16_bf16(vf, fr.v, o1, 0, 0, 0);
                }
            }
        }
    }

    // ---- epilogue: lane owns q-row qg; O^T regs -> d = dt*32 + (r&3)+8*(r>>2)+4*hi ----
    const float inv = 1.f / lsum;
    float* orow = out + ((long)b * T_ + qg) * E_ + h * HS_;
#pragma unroll
    for (int rg = 0; rg < 4; ++rg) {
        float4 v0, v1;
        v0.x = o0[rg * 4 + 0] * inv; v0.y = o0[rg * 4 + 1] * inv;
        v0.z = o0[rg * 4 + 2] * inv; v0.w = o0[rg * 4 + 3] * inv;
        v1.x = o1[rg * 4 + 0] * inv; v1.y = o1[rg * 4 + 1] * inv;
        v1.z = o1[rg * 4 + 2] * inv; v1.w = o1[rg * 4 + 3] * inv;
        *(float4*)&orow[8 * rg + 4 * hi]      = v0;
        *(float4*)&orow[32 + 8 * rg + 4 * hi] = v1;
    }
}

extern "C" void kernel_launch(void* const* d_in, const int* in_sizes, int n_in,
                              void* d_out, int out_size, void* d_ws, size_t ws_size,
                              hipStream_t stream) {
    const float* x     = (const float*)d_in[0];   // [4,2048,1024]
    const float* W_qkv = (const float*)d_in[1];   // [3072,1024]
    const float* b_qkv = (const float*)d_in[2];   // [3072]
    float* out = (float*)d_out;                   // [4,2048,1024]

    const long per = (long)64 * T_ * 64;          // 8,388,608 elems
    __hip_bfloat16* Qb = (__hip_bfloat16*)d_ws;
    __hip_bfloat16* Kb = Qb + per;
    __hip_bfloat16* Vt = Kb + per;
    short* Xb = (short*)(Vt + per);
    short* Wb = Xb + (long)M_ * E_;

    const long ncvt = ((long)M_ * E_ + (long)F_ * E_) / 8;
    cvt_bf16<<<(int)(ncvt / 256), 256, 0, stream>>>(x, W_qkv, Xb, Wb);

    qkv_gemm_mfma<<<24 * 64, 256, 0, stream>>>(Xb, Wb, b_qkv, Qb, Kb, Vt);

    attn_mfma2<<<1024, 256, 0, stream>>>(Qb, Kb, Vt, out);
}

// Round 7
// 162.567 us; speedup vs baseline: 61.1910x; 1.0946x over previous
//
#include <hip/hip_runtime.h>
#include <hip/hip_bf16.h>

#define B_   4
#define T_   2048
#define E_   1024
#define NH_  16
#define HS_  64
#define F_   (3 * E_)   // 3072
#define M_   (B_ * T_)  // 8192

typedef short bf16x8 __attribute__((ext_vector_type(8)));
typedef float f32x4  __attribute__((ext_vector_type(4)));
typedef float f32x16 __attribute__((ext_vector_type(16)));

__device__ __forceinline__ short f2bf(float f) {
    __hip_bfloat16 h = __float2bfloat16(f);
    return *reinterpret_cast<short*>(&h);
}

__device__ __forceinline__ bf16x8 pack2(float4 a, float4 b) {
    bf16x8 r;
    r[0] = f2bf(a.x); r[1] = f2bf(a.y); r[2] = f2bf(a.z); r[3] = f2bf(a.w);
    r[4] = f2bf(b.x); r[5] = f2bf(b.y); r[6] = f2bf(b.z); r[7] = f2bf(b.w);
    return r;
}

__device__ __forceinline__ unsigned pkbf(float a, float b) {
    return ((unsigned)(unsigned short)f2bf(a)) | (((unsigned)(unsigned short)f2bf(b)) << 16);
}

__device__ __forceinline__ void gload16(const void* g, void* l) {
    __builtin_amdgcn_global_load_lds(
        (const __attribute__((address_space(1))) unsigned int*)g,
        (__attribute__((address_space(3))) unsigned int*)l, 16, 0, 0);
}

// ---------------- fp32 -> bf16 pre-pass for X and W ----------------
__global__ __launch_bounds__(256) void cvt_bf16(const float* __restrict__ X,
                                                const float* __restrict__ W,
                                                short* __restrict__ Xb,
                                                short* __restrict__ Wb) {
    const long nX = (long)M_ * E_;   // 8388608
    long i = ((long)blockIdx.x * 256 + threadIdx.x) * 8;
    const float* src;
    short* dst;
    long off;
    if (i < nX) { src = X; dst = Xb; off = i; }
    else        { src = W; dst = Wb; off = i - nX; }
    float4 a = *(const float4*)(src + off);
    float4 b = *(const float4*)(src + off + 4);
    *(bf16x8*)(dst + off) = pack2(a, b);
}

// ---------------- QKV GEMM: 256x128 tile, counted-vmcnt pipeline, swizzled LDS ----------------
// 8 waves (2M x 4N). LDS: 2 bufs x (A 32KB + B 16KB) = 96KB.
// Tile t+1 prefetched (6 x global_load_lds dwordx4) while computing tile t; vmcnt(6).
// Barrier discipline: [STAGE t+1][vmcnt(6)][bar] reads+MFMA [bar] -- no vmcnt(0) in loop.
#define NT 16  // K / 64

__global__ __launch_bounds__(512, 2) void qkv_gemm_mfma(const short* __restrict__ Xb,
                                                        const short* __restrict__ Wb,
                                                        const float* __restrict__ bias,
                                                        __hip_bfloat16* __restrict__ Qb,
                                                        __hip_bfloat16* __restrict__ Kb,
                                                        __hip_bfloat16* __restrict__ Vt) {
    __shared__ __align__(16) short lds[2 * 24576];   // 96 KB

    const int tid = threadIdx.x;
    const int w = tid >> 6, l = tid & 63;
    const int lg = l >> 4, lr = l & 15;
    const int wm = w >> 2, wn = w & 3;

    // bijective XCD swizzle: 768 blocks, 96 per XCD (4 bm-panels x 24 bn)
    const int bid = blockIdx.x;
    const int sw = (bid & 7) * 96 + (bid >> 3);
    const int bm = sw / 24, bn = sw % 24;

    // staging: LDS dest linear (wave-uniform base + lane*16B), source chunk pre-swizzled:
    // LDS[r][c] = G[r][c ^ (r&7)]
    const int srow = tid >> 3;            // 0..63
    const int scs  = (tid & 7) ^ (srow & 7);
    const short* ga0 = Xb + ((long)(bm * 256 +   0 + srow)) * E_ + scs * 8;
    const short* ga1 = Xb + ((long)(bm * 256 +  64 + srow)) * E_ + scs * 8;
    const short* ga2 = Xb + ((long)(bm * 256 + 128 + srow)) * E_ + scs * 8;
    const short* ga3 = Xb + ((long)(bm * 256 + 192 + srow)) * E_ + scs * 8;
    const short* gb0 = Wb + ((long)(bn * 128 +   0 + srow)) * E_ + scs * 8;
    const short* gb1 = Wb + ((long)(bn * 128 +  64 + srow)) * E_ + scs * 8;
    const int dA = 8 * w * 64;            // wave stripe within each 64-row region
    const f32x4 zero = {0.f, 0.f, 0.f, 0.f};
    f32x4 acc[8][2];
#pragma unroll
    for (int mg = 0; mg < 8; ++mg) { acc[mg][0] = zero; acc[mg][1] = zero; }

#define STAGE(t, p)                                                                  \
    {                                                                                \
        const int ko = (t) * 64;                                                     \
        short* lb = &lds[(p) * 24576];                                               \
        gload16(ga0 + ko, &lb[(0 * 64) * 64 + dA]);                                  \
        gload16(ga1 + ko, &lb[(1 * 64) * 64 + dA]);                                  \
        gload16(ga2 + ko, &lb[(2 * 64) * 64 + dA]);                                  \
        gload16(ga3 + ko, &lb[(3 * 64) * 64 + dA]);                                  \
        gload16(gb0 + ko, &lb[16384 + (0 * 64) * 64 + dA]);                          \
        gload16(gb1 + ko, &lb[16384 + (1 * 64) * 64 + dA]);                          \
    }

    STAGE(0, 0);

    for (int t = 0; t < NT; ++t) {
        const int p = t & 1;
        if (t + 1 < NT) {
            STAGE(t + 1, p ^ 1);
            asm volatile("s_waitcnt vmcnt(6)" ::: "memory");   // own tile-t loads landed
        } else {
            asm volatile("s_waitcnt vmcnt(0)" ::: "memory");
        }
        __builtin_amdgcn_s_barrier();        // tile t resident for ALL waves
        __builtin_amdgcn_sched_barrier(0);

        const short* lA = &lds[p * 24576];
        const short* lB = &lds[p * 24576 + 16384];
        bf16x8 af[8][2], bf[2][2];
#pragma unroll
        for (int ng = 0; ng < 2; ++ng)
#pragma unroll
            for (int kk = 0; kk < 2; ++kk)
                bf[ng][kk] = *(const bf16x8*)&lB[(wn * 32 + ng * 16 + lr) * 64 + ((kk * 4 + lg) ^ (lr & 7)) * 8];
#pragma unroll
        for (int mg = 0; mg < 8; ++mg)
#pragma unroll
            for (int kk = 0; kk < 2; ++kk)
                af[mg][kk] = *(const bf16x8*)&lA[(wm * 128 + mg * 16 + lr) * 64 + ((kk * 4 + lg) ^ (lr & 7)) * 8];

        __builtin_amdgcn_s_setprio(1);
#pragma unroll
        for (int mg = 0; mg < 8; ++mg)
#pragma unroll
            for (int ng = 0; ng < 2; ++ng) {
                acc[mg][ng] = __builtin_amdgcn_mfma_f32_16x16x32_bf16(af[mg][0], bf[ng][0], acc[mg][ng], 0, 0, 0);
                acc[mg][ng] = __builtin_amdgcn_mfma_f32_16x16x32_bf16(af[mg][1], bf[ng][1], acc[mg][ng], 0, 0, 0);
            }
        __builtin_amdgcn_s_setprio(0);
        __builtin_amdgcn_s_barrier();        // all waves done reading buf p (lgkm drained by MFMA use)
        __builtin_amdgcn_sched_barrier(0);   // pin: next STAGE stays below
    }

    // epilogue: bn 0-7 -> Q, 8-15 -> K, 16-23 -> V^T
    const int sec = bn >> 3;
#pragma unroll
    for (int mg = 0; mg < 8; ++mg)
#pragma unroll
        for (int ng = 0; ng < 2; ++ng)
#pragma unroll
            for (int r = 0; r < 4; ++r) {
                int row = bm * 256 + wm * 128 + mg * 16 + 4 * lg + r;  // 0..8191
                int col = bn * 128 + wn * 32 + ng * 16 + lr;           // 0..3071
                int cl = col & 1023;
                int h = cl >> 6, d = cl & 63;
                int b = row >> 11, tt = row & 2047;
                int bh = b * 16 + h;
                float v = acc[mg][ng][r] + bias[col];
                if (sec == 0)
                    Qb[((long)bh * T_ + tt) * 64 + d] = __float2bfloat16(v * 0.125f);
                else if (sec == 1)
                    Kb[((long)bh * T_ + tt) * 64 + d] = __float2bfloat16(v);
                else
                    Vt[((long)bh * 64 + d) * T_ + tt] = __float2bfloat16(v);
            }
#undef STAGE
}

// ---------------- Flash attention v2: swapped QK^T, in-register softmax ----------------
__global__ __launch_bounds__(256, 3) void attn_mfma2(const __hip_bfloat16* __restrict__ Qb,
                                                     const __hip_bfloat16* __restrict__ Kb,
                                                     const __hip_bfloat16* __restrict__ Vt,
                                                     float* __restrict__ out) {
    const int g = blockIdx.x;                 // 0..1023
    const int xcd = g & 7, kidx = g >> 3;     // 8 bh per XCD -> 4MB KV fits its L2
    const int bh = xcd * 8 + (kidx & 7);
    const int qt = 15 - (kidx >> 3);          // big tiles dispatch first
    const int b = bh >> 4, h = bh & 15;
    const int tid = threadIdx.x;
    const int wv = tid >> 6, ln = tid & 63;
    const int hi = ln >> 5, q5 = ln & 31;

    __shared__ __align__(16) short K_lds[64 * 64];   // [key][dim] swizzled
    __shared__ __align__(16) short Vt_lds[64 * 64];  // [dim][key] swizzled

    const short* qbase = (const short*)Qb + (long)bh * T_ * 64;
    const short* kbase = (const short*)Kb + (long)bh * T_ * 64;
    const short* vbase = (const short*)Vt + (long)bh * 64 * T_;

    const int wq0 = qt * 128 + wv * 32;
    const int qg = wq0 + q5;

    bf16x8 qf[4];
#pragma unroll
    for (int w = 0; w < 4; ++w)
        qf[w] = *(const bf16x8*)&qbase[(long)qg * 64 + w * 16 + hi * 8];

    const f32x16 zero16 = {0.f,0.f,0.f,0.f, 0.f,0.f,0.f,0.f, 0.f,0.f,0.f,0.f, 0.f,0.f,0.f,0.f};
    f32x16 o0 = zero16, o1 = zero16;
    float mrun = -1e30f, lsum = 0.f;

    const int nkt = 2 * qt + 2;
    for (int kt = 0; kt < nkt; ++kt) {
        __syncthreads();
        {
            int key = tid >> 2, c0 = (tid & 3) * 2;
            const short* kp = &kbase[(long)(kt * 64 + key) * 64 + c0 * 8];
            bf16x8 u0 = *(const bf16x8*)kp;
            bf16x8 u1 = *(const bf16x8*)(kp + 8);
            *(bf16x8*)&K_lds[key * 64 + ((c0    ) ^ (key & 7)) * 8] = u0;
            *(bf16x8*)&K_lds[key * 64 + ((c0 + 1) ^ (key & 7)) * 8] = u1;
        }
        {
            int d = tid >> 2, c0 = (tid & 3) * 2;
            const short* vp = &vbase[(long)d * T_ + kt * 64 + c0 * 8];
            bf16x8 u0 = *(const bf16x8*)vp;
            bf16x8 u1 = *(const bf16x8*)(vp + 8);
            *(bf16x8*)&Vt_lds[d * 64 + ((c0    ) ^ (d & 7)) * 8] = u0;
            *(bf16x8*)&Vt_lds[d * 64 + ((c0 + 1) ^ (d & 7)) * 8] = u1;
        }
        __syncthreads();

        if (kt * 64 > wq0 + 31) continue;
        const bool act1 = (kt * 64 + 32) <= (wq0 + 31);

        f32x16 sa = zero16, sb = zero16;
#pragma unroll
        for (int w = 0; w < 4; ++w) {
            int key = q5;
            bf16x8 kf = *(const bf16x8*)&K_lds[key * 64 + (((w * 2 + hi)) ^ (key & 7)) * 8];
            sa = __builtin_amdgcn_mfma_f32_32x32x16_bf16(kf, qf[w], sa, 0, 0, 0);
        }
        if (act1) {
#pragma unroll
            for (int w = 0; w < 4; ++w) {
                int key = 32 + q5;
                bf16x8 kf = *(const bf16x8*)&K_lds[key * 64 + (((w * 2 + hi)) ^ (key & 7)) * 8];
                sb = __builtin_amdgcn_mfma_f32_32x32x16_bf16(kf, qf[w], sb, 0, 0, 0);
            }
        }

        if (kt * 64 + 31 > wq0) {
#pragma unroll
            for (int r = 0; r < 16; ++r) {
                int key = kt * 64 + (r & 3) + 8 * (r >> 2) + 4 * hi;
                sa[r] = (key <= qg) ? sa[r] : -1e30f;
            }
        }
        if (act1 && (kt * 64 + 63 > wq0)) {
#pragma unroll
            for (int r = 0; r < 16; ++r) {
                int key = kt * 64 + 32 + (r & 3) + 8 * (r >> 2) + 4 * hi;
                sb[r] = (key <= qg) ? sb[r] : -1e30f;
            }
        }

        float tmax = sa[0];
#pragma unroll
        for (int r = 1; r < 16; ++r) tmax = fmaxf(tmax, sa[r]);
        if (act1) {
#pragma unroll
            for (int r = 0; r < 16; ++r) tmax = fmaxf(tmax, sb[r]);
        }
        tmax = fmaxf(tmax, __shfl_xor(tmax, 32, 64));
        const float mn = fmaxf(mrun, tmax);
        const float alpha = __expf(mrun - mn);
        mrun = mn;
        float rs = 0.f;
#pragma unroll
        for (int r = 0; r < 16; ++r) { sa[r] = __expf(sa[r] - mn); rs += sa[r]; }
        if (act1) {
#pragma unroll
            for (int r = 0; r < 16; ++r) { sb[r] = __expf(sb[r] - mn); rs += sb[r]; }
        }
        rs += __shfl_xor(rs, 32, 64);
        lsum = lsum * alpha + rs;
        o0 = o0 * alpha;
        o1 = o1 * alpha;

#pragma unroll
        for (int st = 0; st < 2; ++st) {
            if (st == 1 && !act1) break;
            const f32x16& s = (st == 0) ? sa : sb;
            unsigned pkv[8];
#pragma unroll
            for (int i = 0; i < 8; ++i) pkv[i] = pkbf(s[2 * i], s[2 * i + 1]);
#pragma unroll
            for (int ks = 0; ks < 2; ++ks) {
                unsigned x1 = (unsigned)__shfl_xor((int)(hi ? pkv[4 * ks]     : pkv[4 * ks + 2]), 32, 64);
                unsigned x2 = (unsigned)__shfl_xor((int)(hi ? pkv[4 * ks + 1] : pkv[4 * ks + 3]), 32, 64);
                union { unsigned u[4]; bf16x8 v; } fr;
                fr.u[0] = hi ? x1 : pkv[4 * ks];
                fr.u[1] = hi ? x2 : pkv[4 * ks + 1];
                fr.u[2] = hi ? pkv[4 * ks + 2] : x1;
                fr.u[3] = hi ? pkv[4 * ks + 3] : x2;
                {
                    int d = q5;
                    bf16x8 vf = *(const bf16x8*)&Vt_lds[d * 64 + ((st * 4 + ks * 2 + hi) ^ (d & 7)) * 8];
                    o0 = __builtin_amdgcn_mfma_f32_32x32x16_bf16(vf, fr.v, o0, 0, 0, 0);
                }
                {
                    int d = 32 + q5;
                    bf16x8 vf = *(const bf16x8*)&Vt_lds[d * 64 + ((st * 4 + ks * 2 + hi) ^ (d & 7)) * 8];
                    o1 = __builtin_amdgcn_mfma_f32_32x32x16_bf16(vf, fr.v, o1, 0, 0, 0);
                }
            }
        }
    }

    const float inv = 1.f / lsum;
    float* orow = out + ((long)b * T_ + qg) * E_ + h * HS_;
#pragma unroll
    for (int rg = 0; rg < 4; ++rg) {
        float4 v0, v1;
        v0.x = o0[rg * 4 + 0] * inv; v0.y = o0[rg * 4 + 1] * inv;
        v0.z = o0[rg * 4 + 2] * inv; v0.w = o0[rg * 4 + 3] * inv;
        v1.x = o1[rg * 4 + 0] * inv; v1.y = o1[rg * 4 + 1] * inv;
        v1.z = o1[rg * 4 + 2] * inv; v1.w = o1[rg * 4 + 3] * inv;
        *(float4*)&orow[8 * rg + 4 * hi]      = v0;
        *(float4*)&orow[32 + 8 * rg + 4 * hi] = v1;
    }
}

extern "C" void kernel_launch(void* const* d_in, const int* in_sizes, int n_in,
                              void* d_out, int out_size, void* d_ws, size_t ws_size,
                              hipStream_t stream) {
    const float* x     = (const float*)d_in[0];   // [4,2048,1024]
    const float* W_qkv = (const float*)d_in[1];   // [3072,1024]
    const float* b_qkv = (const float*)d_in[2];   // [3072]
    float* out = (float*)d_out;                   // [4,2048,1024]

    const long per = (long)64 * T_ * 64;          // 8,388,608 elems
    __hip_bfloat16* Qb = (__hip_bfloat16*)d_ws;
    __hip_bfloat16* Kb = Qb + per;
    __hip_bfloat16* Vt = Kb + per;
    short* Xb = (short*)(Vt + per);
    short* Wb = Xb + (long)M_ * E_;

    const long ncvt = ((long)M_ * E_ + (long)F_ * E_) / 8;
    cvt_bf16<<<(int)(ncvt / 256), 256, 0, stream>>>(x, W_qkv, Xb, Wb);

    qkv_gemm_mfma<<<768, 512, 0, stream>>>(Xb, Wb, b_qkv, Qb, Kb, Vt);

    attn_mfma2<<<1024, 256, 0, stream>>>(Qb, Kb, Vt, out);
}